// Round 1
// baseline (817.999 us; speedup 1.0000x reference)
//
#include <hip/hip_runtime.h>

#define H      4096
#define NE     160
#define BM     64
#define BK     32
#define NTILES (H / BK)   // 128
#define NTHR   256

// d_out layout (all float32): [0,98304) topk_idx, [98304,196608) topk_weight, [196608] aux_loss

__global__ __launch_bounds__(NTHR) void gate_kernel(
    const float* __restrict__ x, const float* __restrict__ w,
    float* __restrict__ outIdx, float* __restrict__ outW,
    float* __restrict__ gcnt, float* __restrict__ gssum)
{
    // union'd LDS: staging (xsT 32x64 @0 = 2048 floats, wsT 32x160 @2048 = 5120 floats, total 7168)
    // then reused as logits [64][161] = 10304 floats
    __shared__ float s_all[64 * 161];
    __shared__ float s_mx[64], s_inv[64];
    __shared__ int   s_cnt[NE];

    const int tid  = threadIdx.x;
    const int row0 = blockIdx.x * BM;

    if (tid < NE) s_cnt[tid] = 0;

    // staging mapping (x): token tx, k-chunk cx (8 floats)
    const int tx = tid >> 2;   // 0..63
    const int cx = tid & 3;    // 0..3
    // compute mapping: 2 tokens (2r,2r+1) x 20 experts (20c..20c+19)
    const int r = tid >> 3;    // 0..31
    const int c = tid & 7;     // 0..7

    float acc0[20], acc1[20];
#pragma unroll
    for (int j = 0; j < 20; ++j) { acc0[j] = 0.f; acc1[j] = 0.f; }

    // prefetch tile 0 into registers
    float4 px0, px1, pw[5];
    {
        const float* px = x + (size_t)(row0 + tx) * H + cx * 8;
        px0 = *(const float4*)(px);
        px1 = *(const float4*)(px + 4);
#pragma unroll
        for (int p = 0; p < 5; ++p) {
            int s = tid + NTHR * p;
            pw[p] = *(const float4*)(w + (size_t)(s >> 3) * H + (s & 7) * 4);
        }
    }

    for (int kt = 0; kt < NTILES; ++kt) {
        __syncthreads();
        // store prefetched tile to LDS (k-major)
        {
            int kb = cx * 8;
            s_all[(kb + 0) * 64 + tx] = px0.x;
            s_all[(kb + 1) * 64 + tx] = px0.y;
            s_all[(kb + 2) * 64 + tx] = px0.z;
            s_all[(kb + 3) * 64 + tx] = px0.w;
            s_all[(kb + 4) * 64 + tx] = px1.x;
            s_all[(kb + 5) * 64 + tx] = px1.y;
            s_all[(kb + 6) * 64 + tx] = px1.z;
            s_all[(kb + 7) * 64 + tx] = px1.w;
#pragma unroll
            for (int p = 0; p < 5; ++p) {
                int s  = tid + NTHR * p;
                int e  = s >> 3;
                int kb2 = (s & 7) * 4;
                s_all[2048 + (kb2 + 0) * NE + e] = pw[p].x;
                s_all[2048 + (kb2 + 1) * NE + e] = pw[p].y;
                s_all[2048 + (kb2 + 2) * NE + e] = pw[p].z;
                s_all[2048 + (kb2 + 3) * NE + e] = pw[p].w;
            }
        }
        // prefetch next tile
        if (kt + 1 < NTILES) {
            int k0 = (kt + 1) * BK;
            const float* px = x + (size_t)(row0 + tx) * H + k0 + cx * 8;
            px0 = *(const float4*)(px);
            px1 = *(const float4*)(px + 4);
#pragma unroll
            for (int p = 0; p < 5; ++p) {
                int s = tid + NTHR * p;
                pw[p] = *(const float4*)(w + (size_t)(s >> 3) * H + k0 + (s & 7) * 4);
            }
        }
        __syncthreads();
        // compute
#pragma unroll 4
        for (int k = 0; k < BK; ++k) {
            float2 xv = *(const float2*)&s_all[k * 64 + 2 * r];
            const float* wr = &s_all[2048 + k * NE + 20 * c];
#pragma unroll
            for (int j2 = 0; j2 < 10; ++j2) {
                float2 wv = *(const float2*)&wr[2 * j2];
                acc0[2 * j2]     = fmaf(xv.x, wv.x, acc0[2 * j2]);
                acc0[2 * j2 + 1] = fmaf(xv.x, wv.y, acc0[2 * j2 + 1]);
                acc1[2 * j2]     = fmaf(xv.y, wv.x, acc1[2 * j2]);
                acc1[2 * j2 + 1] = fmaf(xv.y, wv.y, acc1[2 * j2 + 1]);
            }
        }
    }

    __syncthreads();
    // dump logits to LDS [64][161]
#pragma unroll
    for (int j = 0; j < 20; ++j) {
        s_all[(2 * r + 0) * 161 + 20 * c + j] = acc0[j];
        s_all[(2 * r + 1) * 161 + 20 * c + j] = acc1[j];
    }
    __syncthreads();

    // per-token softmax + group top-3 + expert top-6 (threads 0..63, one token each)
    if (tid < 64) {
        const float* L = &s_all[tid * 161];
        float gmax[8];
        float mx = -3.4e38f;
#pragma unroll
        for (int g = 0; g < 8; ++g) {
            float m = L[g * 20];
            for (int j = 1; j < 20; ++j) m = fmaxf(m, L[g * 20 + j]);
            gmax[g] = m;
            mx = fmaxf(mx, m);
        }
        float sum = 0.f;
        for (int e = 0; e < NE; ++e) sum += __expf(L[e] - mx);
        float inv = 1.0f / sum;
        s_mx[tid]  = mx;
        s_inv[tid] = inv;

        // top-3 groups, lax.top_k tie semantics: (value desc, index asc)
        unsigned sel = 0;
        float pv = 3.4e38f; int pi = -1;
        for (int it = 0; it < 3; ++it) {
            float bv = -3.4e38f; int bi = 0;
            for (int g = 0; g < 8; ++g) {
                float v = gmax[g];
                bool below = (v < pv) || (v == pv && g > pi);
                if (below && v > bv) { bv = v; bi = g; }
            }
            sel |= 1u << bi;
            pv = bv; pi = bi;
        }

        // top-6 experts within selected groups
        const int tok = row0 + tid;
        float pv2 = 3.4e38f; int pi2 = -1;
        for (int it = 0; it < 6; ++it) {
            float bv = -3.4e38f; int bi = 0;
            for (int g = 0; g < 8; ++g) {
                if (!((sel >> g) & 1u)) continue;
                for (int j = 0; j < 20; ++j) {
                    int e = g * 20 + j;
                    float v = L[e];
                    bool below = (v < pv2) || (v == pv2 && e > pi2);
                    if (below && v > bv) { bv = v; bi = e; }
                }
            }
            pv2 = bv; pi2 = bi;
            outIdx[(size_t)tok * 6 + it] = (float)bi;
            outW[(size_t)tok * 6 + it]   = __expf(bv - mx) * inv * 16.0f;
            atomicAdd(&s_cnt[bi], 1);
        }
    }
    __syncthreads();

    // per-block expert score-sum + counts -> global (batch, expert) bins
    if (tid < NE) {
        float ss = 0.f;
        for (int t2 = 0; t2 < 64; ++t2)
            ss += __expf(s_all[t2 * 161 + tid] - s_mx[t2]) * s_inv[t2];
        const int b = row0 >> 12;   // 4096 tokens per batch
        atomicAdd(&gssum[b * NE + tid], ss);
        atomicAdd(&gcnt[b * NE + tid], (float)s_cnt[tid]);
    }
}

__global__ __launch_bounds__(64) void aux_kernel(
    const float* __restrict__ gcnt, const float* __restrict__ gssum,
    float* __restrict__ out)
{
    const int lane = threadIdx.x;
    float part = 0.f;
    if (lane < 32) {
        const int b = lane >> 3, g = lane & 7;
        const float* cn = gcnt  + b * NE + g * 20;
        const float* sm = gssum + b * NE + g * 20;
        float s1 = 0.f, sc = 0.f, sms = 0.f;
        for (int j = 0; j < 20; ++j) {
            float ce = cn[j] * (1.0f / 153.6f);   // counts / (s*k/E)
            float ms = sm[j] * (1.0f / 4096.0f);  // mean over s
            s1  += ce * ms;
            sc  += cn[j];
            sms += ms;
        }
        float ceg = sc * (1.0f / 153.6f) * (1.0f / 20.0f);
        float msg = sms * (1.0f / 20.0f);
        float ce2 = sc * (1.0f / 1536.0f);        // counts_g / (M*s/G)
        part = s1 + ceg * msg + ce2 * msg;
    }
#pragma unroll
    for (int off = 32; off > 0; off >>= 1) part += __shfl_down(part, off);
    if (lane == 0) out[0] = part * (0.001f * 0.25f);  // ALPHA * mean over B=4
}

extern "C" void kernel_launch(void* const* d_in, const int* in_sizes, int n_in,
                              void* d_out, int out_size, void* d_ws, size_t ws_size,
                              hipStream_t stream)
{
    (void)in_sizes; (void)n_in; (void)out_size; (void)ws_size;
    const float* x = (const float*)d_in[0];
    const float* w = (const float*)d_in[1];
    float* out   = (float*)d_out;
    float* gcnt  = (float*)d_ws;          // [4][160]
    float* gssum = gcnt + 4 * NE;         // [4][160]

    hipMemsetAsync(d_ws, 0, 2 * 4 * NE * sizeof(float), stream);

    gate_kernel<<<16384 / BM, NTHR, 0, stream>>>(
        x, w, out, out + 98304, gcnt, gssum);
    aux_kernel<<<1, 64, 0, stream>>>(gcnt, gssum, out + 196608);
}